// Round 6
// baseline (85.933 us; speedup 1.0000x reference)
//
#include <hip/hip_runtime.h>

// Problem constants (from reference)
#define V 49688
#define D 128
#define B 16
#define N 100
#define VD (V * D)        // 6,360,064 floats per batch
#define VD4 (VD / 4)      // 1,590,016 float4 per batch (= 2048*776 + 768)

typedef float f32x4 __attribute__((ext_vector_type(4)));

// Kernel 1 (R6): NT broadcast, ILP=8.
// Ladder: R2 NT-broadcast=88, R5 +ILP4=79.9. Mechanism confirmed: deeper
// MLP / bigger per-region bursts -> higher NT write BW. This round: 8 float4
// per thread (8 loads in flight, then 8x 1KB consecutive wave-bursts per
// batch region). 777 blocks; only the last is guarded.
__global__ __launch_bounds__(256) void GlobalGatedUpdate_copy_kernel(
    const f32x4* __restrict__ W4, f32x4* __restrict__ out4) {
  int c = blockIdx.x * 2048 + threadIdx.x;   // base f4 index of this thread
  f32x4 v[8];
  if (c + 7 * 256 < VD4) {                   // full block (blocks 0..775)
    #pragma unroll
    for (int k = 0; k < 8; ++k) v[k] = W4[c + k * 256];
    #pragma unroll
    for (int b = 0; b < B; ++b) {
      f32x4* dst = out4 + (size_t)b * VD4 + c;
      #pragma unroll
      for (int k = 0; k < 8; ++k)
        __builtin_nontemporal_store(v[k], dst + k * 256);
    }
  } else {                                   // tail block (776): guarded
    bool g[8];
    #pragma unroll
    for (int k = 0; k < 8; ++k) {
      g[k] = (c + k * 256) < VD4;
      if (g[k]) v[k] = W4[c + k * 256];
    }
    #pragma unroll
    for (int b = 0; b < B; ++b) {
      f32x4* dst = out4 + (size_t)b * VD4 + c;
      #pragma unroll
      for (int k = 0; k < 8; ++k)
        if (g[k]) __builtin_nontemporal_store(v[k], dst + k * 256);
    }
  }
}

// Kernel 2: for each (b, i): v = nodes[b*N+i];
//   out[b][v][:] = (1 - alpha[v]) * W[v][:] + alpha[v] * x[i][:]
__global__ __launch_bounds__(256) void GlobalGatedUpdate_scatter_kernel(
    const int* __restrict__ nodes, const float* __restrict__ x,
    const float* __restrict__ W, const float* __restrict__ alpha,
    float* __restrict__ out) {
  int t = blockIdx.x * 256 + threadIdx.x;            // 0 .. B*N*32 - 1
  int d4  = t & 31;                                  // float4 index within row
  int row = t >> 5;                                  // 0 .. 1599 (= b*N + i)
  int b = row / N;
  int i = row - b * N;                               // position in node list -> x row
  int v = nodes[row];
  float a = alpha[v];                                // alpha is (V,1)
  f32x4 wv = ((const f32x4*)W)[v * 32 + d4];
  f32x4 xv = ((const f32x4*)x)[i * 32 + d4];
  f32x4 res = (1.0f - a) * wv + a * xv;
  ((f32x4*)out)[(size_t)b * (size_t)VD4 + (size_t)(v * 32 + d4)] = res;
}

extern "C" void kernel_launch(void* const* d_in, const int* in_sizes, int n_in,
                              void* d_out, int out_size, void* d_ws, size_t ws_size,
                              hipStream_t stream) {
  const int*   nodes = (const int*)d_in[0];   // (B, N) int32
  const float* x     = (const float*)d_in[1]; // (B*N, D) f32
  const float* W     = (const float*)d_in[2]; // (V, D) f32
  const float* alpha = (const float*)d_in[3]; // (V, 1) f32
  float* out = (float*)d_out;                 // (B, V, D) f32

  GlobalGatedUpdate_copy_kernel<<<(VD4 + 2047) / 2048, 256, 0, stream>>>(
      (const f32x4*)W, (f32x4*)out);

  GlobalGatedUpdate_scatter_kernel<<<(B * N * 32) / 256, 256, 0, stream>>>(
      nodes, x, W, alpha, out);
}